// Round 1
// baseline (197.012 us; speedup 1.0000x reference)
//
#include <hip/hip_runtime.h>
#include <math.h>

#define BATCH 16384

// Fused: conv1(1->4,3x3,pad1)+relu+pool2 -> conv2(4->4,3x3,pad1)+relu+pool2
//        -> linear(196->16) -> 4-qubit circuit -> readout(4) -> pre-BN out + stats
// One wave (64 lanes) per sample; 4 samples per 256-thread block.
__global__ __launch_bounds__(256) void qnat_fused(
    const float* __restrict__ x,    // (B,1,28,28)
    const float* __restrict__ w1,   // (4,1,3,3)
    const float* __restrict__ b1,   // (4,)
    const float* __restrict__ w2,   // (4,4,3,3)
    const float* __restrict__ b2,   // (4,)
    const float* __restrict__ plw,  // (16,196)
    const float* __restrict__ plb,  // (16,)
    const float* __restrict__ rw,   // (4,4)
    const float* __restrict__ rb,   // (4,)
    float* __restrict__ pre,        // (B,4)  pre-BN output (lives in d_out)
    float* __restrict__ stats)      // [8]  {sum_c, sumsq_c}
{
  __shared__ float s_w1[36];
  __shared__ float s_b1[4];
  __shared__ float s_w2[144];
  __shared__ float s_b2[4];
  __shared__ float xs[4][900];          // 30x30 zero-padded input per sample
  __shared__ float h1p[4][4][16][18];   // conv1-pooled, zero-padded, row stride 18 (bank-aliasing break)
  __shared__ float h2[4][196];          // conv2-pooled flat (c*49+y*7+x)
  __shared__ float sc[4][2][16];        // cos(p/2), sin(p/2) per param
  __shared__ float s_red[8];            // block-local BN sums

  const int tid = threadIdx.x;
  const int w = tid >> 6;               // wave id = sample slot
  const int lane = tid & 63;
  const int sample = blockIdx.x * 4 + w;

  // ---- block-shared weight staging + reduction init ----
  if (tid < 144)      s_w2[tid] = w2[tid];
  else if (tid < 180) s_w1[tid - 144] = w1[tid - 144];
  else if (tid < 184) s_b1[tid - 180] = b1[tid - 180];
  else if (tid < 188) s_b2[tid - 184] = b2[tid - 184];
  else if (tid < 196) s_red[tid - 188] = 0.0f;

  // ---- phase A: zero padded buffers ----
  for (int p = lane; p < 900; p += 64) xs[w][p] = 0.0f;
  {
    float* h1f = &h1p[w][0][0][0];
    for (int p = lane; p < 4 * 16 * 18; p += 64) h1f[p] = 0.0f;
  }
  __syncthreads();

  // ---- phase B: load x into padded interior ----
  {
    const float* xb = x + (size_t)sample * 784;
    for (int p = lane; p < 784; p += 64) {
      int r = p / 28;
      int cc = p - r * 28;
      xs[w][(r + 1) * 30 + (cc + 1)] = xb[p];
    }
  }
  __syncthreads();

  // ---- phase C: conv1 + relu + maxpool2 -> h1p interior ----
  for (int p = lane; p < 784; p += 64) {
    int c = p / 196;
    int rem = p - c * 196;
    int i = rem / 14;
    int j = rem - i * 14;
    const float* base = &xs[w][2 * i * 30 + 2 * j];
    float patch[4][4];
    #pragma unroll
    for (int dy = 0; dy < 4; dy++) {
      float2 a = *(const float2*)(base + dy * 30);
      float2 bb = *(const float2*)(base + dy * 30 + 2);
      patch[dy][0] = a.x; patch[dy][1] = a.y; patch[dy][2] = bb.x; patch[dy][3] = bb.y;
    }
    float wv[9];
    #pragma unroll
    for (int t = 0; t < 9; t++) wv[t] = s_w1[c * 9 + t];
    const float bias = s_b1[c];
    float mx = 0.0f;  // relu(max(conv)) == max(0, max(conv))
    #pragma unroll
    for (int py = 0; py < 2; py++)
      #pragma unroll
      for (int px = 0; px < 2; px++) {
        float acc = bias;
        #pragma unroll
        for (int dy = 0; dy < 3; dy++)
          #pragma unroll
          for (int dx = 0; dx < 3; dx++)
            acc = fmaf(patch[py + dy][px + dx], wv[dy * 3 + dx], acc);
        mx = fmaxf(mx, acc);
      }
    h1p[w][c][i + 1][j + 1] = mx;
  }
  __syncthreads();

  // ---- phase D: conv2 + relu + maxpool2 -> h2 (flatten layout) ----
  for (int p = lane; p < 196; p += 64) {
    int co = p / 49;
    int rem = p - co * 49;
    int i = rem / 7;
    int j = rem - i * 7;
    float acc00 = s_b2[co], acc01 = acc00, acc10 = acc00, acc11 = acc00;
    #pragma unroll
    for (int ci = 0; ci < 4; ci++) {
      const float* hb = &h1p[w][ci][2 * i][2 * j];
      float patch[4][4];
      #pragma unroll
      for (int dy = 0; dy < 4; dy++) {
        float2 a = *(const float2*)(hb + dy * 18);
        float2 bb = *(const float2*)(hb + dy * 18 + 2);
        patch[dy][0] = a.x; patch[dy][1] = a.y; patch[dy][2] = bb.x; patch[dy][3] = bb.y;
      }
      const float* wv = &s_w2[(co * 4 + ci) * 9];
      #pragma unroll
      for (int dy = 0; dy < 3; dy++)
        #pragma unroll
        for (int dx = 0; dx < 3; dx++) {
          float ww = wv[dy * 3 + dx];
          acc00 = fmaf(patch[dy][dx],         ww, acc00);
          acc01 = fmaf(patch[dy][dx + 1],     ww, acc01);
          acc10 = fmaf(patch[dy + 1][dx],     ww, acc10);
          acc11 = fmaf(patch[dy + 1][dx + 1], ww, acc11);
        }
    }
    float mx = fmaxf(fmaxf(acc00, acc01), fmaxf(acc10, acc11));
    h2[w][p] = fmaxf(mx, 0.0f);
  }
  __syncthreads();

  // ---- phase E: linear 196->16, then cos/sin of half-angles ----
  {
    const int k = lane & 15;
    const int part = lane >> 4;  // 0..3, 49 features each
    const float* hh = &h2[w][part * 49];
    const float* wp = plw + k * 196 + part * 49;
    float s = 0.0f;
    #pragma unroll
    for (int f = 0; f < 49; f++) s = fmaf(hh[f], wp[f], s);
    s += __shfl_down(s, 32, 64);
    s += __shfl_down(s, 16, 64);
    if (part == 0) {
      float pv = s + plb[k];
      float sv, cv;
      sincosf(pv * 0.5f, &sv, &cv);
      sc[w][0][k] = cv;
      sc[w][1][k] = sv;
    }
  }
  __syncthreads();

  // ---- phase F: 4-qubit circuit on lanes 0..15 (one complex amp per lane) ----
  if (lane < 16) {
    const int l = lane;  // index = w0*8 + w1*4 + w2*2 + w3; wire i <-> bit (3-i)
    float re = (l == 0) ? 1.0f : 0.0f;
    float im = 0.0f;
    #pragma unroll
    for (int qi = 0; qi < 4; qi++) {
      const int beta = 3 - qi;
      const int m = 1 << beta;
      const int b = (l >> beta) & 1;
      // RY: new = c*own + (b ? s : -s)*partner
      float c = sc[w][0][4 * qi], s = sc[w][1][4 * qi];
      float pr_ = __shfl_xor(re, m, 64), pi_ = __shfl_xor(im, m, 64);
      float sg = b ? s : -s;
      re = fmaf(c, re, sg * pr_);
      im = fmaf(c, im, sg * pi_);
      // RZ: multiply by exp(-i*sigma*th/2), sigma = b? -1 : +1  ->  re' = c*re - sz*im; im' = c*im + sz*re, sz = b? s : -s
      c = sc[w][0][4 * qi + 1]; s = sc[w][1][4 * qi + 1];
      float sz = b ? s : -s;
      float nr = c * re - sz * im;
      float ni = c * im + sz * re;
      re = nr; im = ni;
      // RX: new = c*own + (-i s)*partner -> re' = c*re + s*p.im; im' = c*im - s*p.re
      c = sc[w][0][4 * qi + 2]; s = sc[w][1][4 * qi + 2];
      pr_ = __shfl_xor(re, m, 64); pi_ = __shfl_xor(im, m, 64);
      nr = fmaf(c, re, s * pi_);
      ni = fmaf(c, im, -s * pr_);
      re = nr; im = ni;
      // CNOT(qi -> (qi+1)%4): if control bit set, take target-flipped partner
      const int tm = 1 << (3 - ((qi + 1) & 3));
      float fr = __shfl_xor(re, tm, 64), fi = __shfl_xor(im, tm, 64);
      if (b) { re = fr; im = fi; }
    }
    // PauliZ expvals
    float pr2 = re * re + im * im;
    float z0 = ((l >> 3) & 1) ? -pr2 : pr2;
    float z1 = ((l >> 2) & 1) ? -pr2 : pr2;
    float z2 = ((l >> 1) & 1) ? -pr2 : pr2;
    float z3 = (l & 1) ? -pr2 : pr2;
    #pragma unroll
    for (int off = 8; off >= 1; off >>= 1) {
      z0 += __shfl_xor(z0, off, 64);
      z1 += __shfl_xor(z1, off, 64);
      z2 += __shfl_xor(z2, off, 64);
      z3 += __shfl_xor(z3, off, 64);
    }
    if (l == 0) {
      float o0 = fmaf(rw[0],  z0, fmaf(rw[1],  z1, fmaf(rw[2],  z2, fmaf(rw[3],  z3, rb[0]))));
      float o1 = fmaf(rw[4],  z0, fmaf(rw[5],  z1, fmaf(rw[6],  z2, fmaf(rw[7],  z3, rb[1]))));
      float o2 = fmaf(rw[8],  z0, fmaf(rw[9],  z1, fmaf(rw[10], z2, fmaf(rw[11], z3, rb[2]))));
      float o3 = fmaf(rw[12], z0, fmaf(rw[13], z1, fmaf(rw[14], z2, fmaf(rw[15], z3, rb[3]))));
      *(float4*)(pre + (size_t)sample * 4) = make_float4(o0, o1, o2, o3);
      atomicAdd(&s_red[0], o0); atomicAdd(&s_red[4], o0 * o0);
      atomicAdd(&s_red[1], o1); atomicAdd(&s_red[5], o1 * o1);
      atomicAdd(&s_red[2], o2); atomicAdd(&s_red[6], o2 * o2);
      atomicAdd(&s_red[3], o3); atomicAdd(&s_red[7], o3 * o3);
    }
  }
  __syncthreads();
  if (tid < 8) atomicAdd(&stats[tid], s_red[tid]);
}

// In-place batch-norm over d_out using global stats.
__global__ __launch_bounds__(256) void qnat_bn(
    float* __restrict__ pre,            // (B,4), in d_out; normalized in place
    const float* __restrict__ stats,    // [8]
    const float* __restrict__ bnw,
    const float* __restrict__ bnb)
{
  int idx = blockIdx.x * 256 + threadIdx.x;  // < B*4
  int c = idx & 3;
  float mean = stats[c] * (1.0f / BATCH);
  float ex2 = stats[4 + c] * (1.0f / BATCH);
  float var = ex2 - mean * mean;           // biased variance
  float inv = rsqrtf(var + 1e-5f);
  pre[idx] = (pre[idx] - mean) * inv * bnw[c] + bnb[c];
}

extern "C" void kernel_launch(void* const* d_in, const int* in_sizes, int n_in,
                              void* d_out, int out_size, void* d_ws, size_t ws_size,
                              hipStream_t stream) {
  const float* x   = (const float*)d_in[0];
  const float* w1  = (const float*)d_in[1];
  const float* b1  = (const float*)d_in[2];
  const float* w2  = (const float*)d_in[3];
  const float* b2  = (const float*)d_in[4];
  const float* plw = (const float*)d_in[5];
  const float* plb = (const float*)d_in[6];
  const float* rw  = (const float*)d_in[7];
  const float* rb  = (const float*)d_in[8];
  const float* bnw = (const float*)d_in[9];
  const float* bnb = (const float*)d_in[10];

  float* out   = (float*)d_out;     // pre-BN values written here, normalized in place
  float* stats = (float*)d_ws;      // 8 floats

  hipMemsetAsync(stats, 0, 8 * sizeof(float), stream);
  qnat_fused<<<BATCH / 4, 256, 0, stream>>>(x, w1, b1, w2, b2, plw, plb, rw, rb, out, stats);
  qnat_bn<<<(BATCH * 4) / 256, 256, 0, stream>>>(out, stats, bnw, bnb);
}

// Round 2
// 161.578 us; speedup vs baseline: 1.2193x; 1.2193x over previous
//
#include <hip/hip_runtime.h>
#include <math.h>

#define BATCH 16384

// v2: row-strip-per-lane convs, static indexing, conflict-aware LDS strides.
// One wave per sample, 4 samples per 256-thread block.
__global__ __launch_bounds__(256) void qnat_fused(
    const float* __restrict__ x,    // (B,1,28,28)
    const float* __restrict__ w1,   // (4,1,3,3)
    const float* __restrict__ b1,   // (4,)
    const float* __restrict__ w2,   // (4,4,3,3)
    const float* __restrict__ b2,   // (4,)
    const float* __restrict__ plw,  // (16,196)
    const float* __restrict__ plb,  // (16,)
    const float* __restrict__ rw,   // (4,4)
    const float* __restrict__ rb,   // (4,)
    float* __restrict__ pre,        // (B,4) pre-BN output (in d_out)
    float* __restrict__ stats)      // [8] {sum_c, sumsq_c}
{
  __shared__ float s_w1[36];
  __shared__ float s_b1[4];
  __shared__ float s_w2[144];
  __shared__ float s_b2[4];
  __shared__ float xs[4][30 * 34];      // 30 padded rows x 34 cols (28+2 pad + 4 junk)
  __shared__ float h1p[4][1164];        // 4 ch x (16 rows x 18 cols) + slack, ch stride 290
  __shared__ float h2[4][196];          // conv2-pooled flat c*49 + y*7 + x
  __shared__ float sc[4][2][16];        // cos/sin of half-angles
  __shared__ float s_red[8];

  const int tid = threadIdx.x;
  const int w = tid >> 6;
  const int lane = tid & 63;
  const int sample = blockIdx.x * 4 + w;

  // ---- stage weights + init reduction ----
  if (tid < 144)      s_w2[tid] = w2[tid];
  else if (tid < 180) s_w1[tid - 144] = w1[tid - 144];
  else if (tid < 184) s_b1[tid - 180] = b1[tid - 180];
  else if (tid < 188) s_b2[tid - 184] = b2[tid - 184];
  else if (tid < 196) s_red[tid - 188] = 0.0f;

  // ---- phase A: zero padded buffers (float2) ----
  {
    float2 zz = make_float2(0.f, 0.f);
    float2* xz = (float2*)&xs[w][0];
    for (int p = lane; p < 510; p += 64) xz[p] = zz;
    float2* hz = (float2*)&h1p[w][0];
    for (int p = lane; p < 582; p += 64) hz[p] = zz;
  }
  __syncthreads();

  // ---- phase B: load x (float4 coalesced) into padded interior ----
  {
    const float4* xb = (const float4*)(x + (size_t)sample * 784);
    #pragma unroll
    for (int t = 0; t < 4; t++) {
      int idx = t * 64 + lane;          // float4 index 0..195
      if (idx < 196) {
        float4 v = xb[idx];
        int r = idx / 7;
        int c4 = idx - r * 7;
        float* dst = &xs[w][(r + 1) * 34 + 1 + 4 * c4];
        dst[0] = v.x; dst[1] = v.y; dst[2] = v.z; dst[3] = v.w;
      }
    }
  }
  __syncthreads();

  // ---- phase C: conv1 + relu + pool. lane = (row i, col-quad q), 56 lanes ----
  if (lane < 56) {
    const int i = lane >> 2;            // pooled row 0..13
    const int q = lane & 3;             // col group: pooled cols 4q..4q+3 (q=3: 2 valid)
    float win[4][10];
    #pragma unroll
    for (int r = 0; r < 4; r++) {
      const float2* rp = (const float2*)&xs[w][(2 * i + r) * 34 + 8 * q];
      #pragma unroll
      for (int t = 0; t < 5; t++) {
        float2 v = rp[t];
        win[r][2 * t] = v.x; win[r][2 * t + 1] = v.y;
      }
    }
    #pragma unroll
    for (int c = 0; c < 4; c++) {
      float wv[9];
      #pragma unroll
      for (int t = 0; t < 9; t++) wv[t] = s_w1[c * 9 + t];
      const float bias = s_b1[c];
      #pragma unroll
      for (int jj = 0; jj < 4; jj++) {
        float m = 0.0f;                 // relu folded into max
        #pragma unroll
        for (int py = 0; py < 2; py++)
          #pragma unroll
          for (int px = 0; px < 2; px++) {
            float a = bias;
            #pragma unroll
            for (int dy = 0; dy < 3; dy++)
              #pragma unroll
              for (int dx = 0; dx < 3; dx++)
                a = fmaf(win[py + dy][2 * jj + px + dx], wv[dy * 3 + dx], a);
            m = fmaxf(m, a);
          }
        int col = 4 * q + jj;
        if (col < 14) h1p[w][290 * c + 18 * (i + 1) + 1 + col] = m;
      }
    }
  }
  __syncthreads();

  // ---- phase D: conv2 + relu + pool. lane = i2*8 + jh*4 + co, 56 lanes ----
  if (lane < 56) {
    const int co = lane & 3;
    const int jh = (lane >> 2) & 1;     // col half: pooled cols 4jh.. (jh=1: 3 valid)
    const int i2 = lane >> 3;           // pooled row 0..6
    float acc[2][2][4];
    {
      const float bias = s_b2[co];
      #pragma unroll
      for (int py = 0; py < 2; py++)
        #pragma unroll
        for (int px = 0; px < 2; px++)
          #pragma unroll
          for (int jj = 0; jj < 4; jj++) acc[py][px][jj] = bias;
    }
    #pragma unroll
    for (int ci = 0; ci < 4; ci++) {
      float win[4][10];
      #pragma unroll
      for (int r = 0; r < 4; r++) {
        const float2* rp = (const float2*)&h1p[w][290 * ci + 18 * (2 * i2 + r) + 8 * jh];
        #pragma unroll
        for (int t = 0; t < 5; t++) {
          float2 v = rp[t];
          win[r][2 * t] = v.x; win[r][2 * t + 1] = v.y;
        }
      }
      float wv[9];
      const int wb = (co * 4 + ci) * 9;
      #pragma unroll
      for (int t = 0; t < 9; t++) wv[t] = s_w2[wb + t];
      #pragma unroll
      for (int jj = 0; jj < 4; jj++)
        #pragma unroll
        for (int py = 0; py < 2; py++)
          #pragma unroll
          for (int px = 0; px < 2; px++) {
            float a = acc[py][px][jj];
            #pragma unroll
            for (int dy = 0; dy < 3; dy++)
              #pragma unroll
              for (int dx = 0; dx < 3; dx++)
                a = fmaf(win[py + dy][2 * jj + px + dx], wv[dy * 3 + dx], a);
            acc[py][px][jj] = a;
          }
    }
    #pragma unroll
    for (int jj = 0; jj < 4; jj++) {
      int J = 4 * jh + jj;
      if (J < 7) {
        float m = fmaxf(fmaxf(acc[0][0][jj], acc[0][1][jj]),
                        fmaxf(acc[1][0][jj], acc[1][1][jj]));
        h2[w][49 * co + 7 * i2 + J] = fmaxf(m, 0.0f);
      }
    }
  }
  __syncthreads();

  // ---- phase E: linear 196->16 + half-angle sincos ----
  {
    const int k = lane & 15;
    const int part = lane >> 4;
    const float* hh = &h2[w][part * 49];
    const float* wp = plw + k * 196 + part * 49;
    float s = 0.0f;
    #pragma unroll
    for (int f = 0; f < 49; f++) s = fmaf(hh[f], wp[f], s);
    s += __shfl_down(s, 32, 64);
    s += __shfl_down(s, 16, 64);
    if (part == 0) {
      float pv = s + plb[k];
      float sv, cv;
      __sincosf(pv * 0.5f, &sv, &cv);
      sc[w][0][k] = cv;
      sc[w][1][k] = sv;
    }
  }
  // sc written and read by the same wave's lanes 0..15 — no barrier needed.

  // ---- phase F: 4-qubit circuit on lanes 0..15 ----
  if (lane < 16) {
    const int l = lane;
    float re = (l == 0) ? 1.0f : 0.0f;
    float im = 0.0f;
    #pragma unroll
    for (int qi = 0; qi < 4; qi++) {
      const int beta = 3 - qi;
      const int m = 1 << beta;
      const int b = (l >> beta) & 1;
      float c = sc[w][0][4 * qi], s = sc[w][1][4 * qi];
      float pr_ = __shfl_xor(re, m, 64), pi_ = __shfl_xor(im, m, 64);
      float sg = b ? s : -s;
      re = fmaf(c, re, sg * pr_);
      im = fmaf(c, im, sg * pi_);
      c = sc[w][0][4 * qi + 1]; s = sc[w][1][4 * qi + 1];
      float sz = b ? s : -s;
      float nr = c * re - sz * im;
      float ni = c * im + sz * re;
      re = nr; im = ni;
      c = sc[w][0][4 * qi + 2]; s = sc[w][1][4 * qi + 2];
      pr_ = __shfl_xor(re, m, 64); pi_ = __shfl_xor(im, m, 64);
      nr = fmaf(c, re, s * pi_);
      ni = fmaf(c, im, -s * pr_);
      re = nr; im = ni;
      const int tm = 1 << (3 - ((qi + 1) & 3));
      float fr = __shfl_xor(re, tm, 64), fi = __shfl_xor(im, tm, 64);
      if (b) { re = fr; im = fi; }
    }
    float pr2 = re * re + im * im;
    float z0 = ((l >> 3) & 1) ? -pr2 : pr2;
    float z1 = ((l >> 2) & 1) ? -pr2 : pr2;
    float z2 = ((l >> 1) & 1) ? -pr2 : pr2;
    float z3 = (l & 1) ? -pr2 : pr2;
    #pragma unroll
    for (int off = 8; off >= 1; off >>= 1) {
      z0 += __shfl_xor(z0, off, 64);
      z1 += __shfl_xor(z1, off, 64);
      z2 += __shfl_xor(z2, off, 64);
      z3 += __shfl_xor(z3, off, 64);
    }
    if (l == 0) {
      float o0 = fmaf(rw[0],  z0, fmaf(rw[1],  z1, fmaf(rw[2],  z2, fmaf(rw[3],  z3, rb[0]))));
      float o1 = fmaf(rw[4],  z0, fmaf(rw[5],  z1, fmaf(rw[6],  z2, fmaf(rw[7],  z3, rb[1]))));
      float o2 = fmaf(rw[8],  z0, fmaf(rw[9],  z1, fmaf(rw[10], z2, fmaf(rw[11], z3, rb[2]))));
      float o3 = fmaf(rw[12], z0, fmaf(rw[13], z1, fmaf(rw[14], z2, fmaf(rw[15], z3, rb[3]))));
      *(float4*)(pre + (size_t)sample * 4) = make_float4(o0, o1, o2, o3);
      atomicAdd(&s_red[0], o0); atomicAdd(&s_red[4], o0 * o0);
      atomicAdd(&s_red[1], o1); atomicAdd(&s_red[5], o1 * o1);
      atomicAdd(&s_red[2], o2); atomicAdd(&s_red[6], o2 * o2);
      atomicAdd(&s_red[3], o3); atomicAdd(&s_red[7], o3 * o3);
    }
  }
  __syncthreads();
  if (tid < 8) atomicAdd(&stats[tid], s_red[tid]);
}

__global__ __launch_bounds__(256) void qnat_bn(
    float* __restrict__ pre,
    const float* __restrict__ stats,
    const float* __restrict__ bnw,
    const float* __restrict__ bnb)
{
  int idx = blockIdx.x * 256 + threadIdx.x;
  int c = idx & 3;
  float mean = stats[c] * (1.0f / BATCH);
  float ex2 = stats[4 + c] * (1.0f / BATCH);
  float var = ex2 - mean * mean;
  float inv = rsqrtf(var + 1e-5f);
  pre[idx] = (pre[idx] - mean) * inv * bnw[c] + bnb[c];
}

extern "C" void kernel_launch(void* const* d_in, const int* in_sizes, int n_in,
                              void* d_out, int out_size, void* d_ws, size_t ws_size,
                              hipStream_t stream) {
  const float* x   = (const float*)d_in[0];
  const float* w1  = (const float*)d_in[1];
  const float* b1  = (const float*)d_in[2];
  const float* w2  = (const float*)d_in[3];
  const float* b2  = (const float*)d_in[4];
  const float* plw = (const float*)d_in[5];
  const float* plb = (const float*)d_in[6];
  const float* rw  = (const float*)d_in[7];
  const float* rb  = (const float*)d_in[8];
  const float* bnw = (const float*)d_in[9];
  const float* bnb = (const float*)d_in[10];

  float* out   = (float*)d_out;
  float* stats = (float*)d_ws;

  hipMemsetAsync(stats, 0, 8 * sizeof(float), stream);
  qnat_fused<<<BATCH / 4, 256, 0, stream>>>(x, w1, b1, w2, b2, plw, plb, rw, rb, out, stats);
  qnat_bn<<<(BATCH * 4) / 256, 256, 0, stream>>>(out, stats, bnw, bnb);
}